// Round 1
// baseline (217.322 us; speedup 1.0000x reference)
//
#include <hip/hip_runtime.h>

// DropBlock: out[n,c,h,w] = x[n,c,h,w] * block_mask[h,w] * scale
// block_mask = 1 - maxpool7x7_backward(u < gamma); scale = HW / sum(block_mask)

#define HW    3136   // 56*56
#define WDIM  56
#define HW4   784    // HW/4

// Kernel 1: one workgroup computes the fused multiplier m[h][w] = bm*scale.
__global__ void __launch_bounds__(256) dropblock_mask_kernel(
        const float* __restrict__ u, float* __restrict__ m) {
    __shared__ unsigned char seed[HW];
    __shared__ unsigned char drop[HW];
    __shared__ int s_count;

    // gamma exactly as Python float64 arithmetic, then cast to f32 (JAX weak typing)
    const float gamma = (float)(0.1 / 49.0 * (3136.0 / 2500.0));

    if (threadIdx.x == 0) s_count = 0;
    for (int i = threadIdx.x; i < HW; i += blockDim.x)
        seed[i] = (u[i] < gamma) ? (unsigned char)1 : (unsigned char)0;
    __syncthreads();

    int local = 0;
    for (int i = threadIdx.x; i < HW; i += blockDim.x) {
        int h = i / WDIM, w = i % WDIM;
        int h0 = (h >= 6) ? h - 6 : 0;
        int w0 = (w >= 6) ? w - 6 : 0;
        int d = 0;
        for (int hh = h0; hh <= h; ++hh)
            for (int ww = w0; ww <= w; ++ww)
                d |= (int)seed[hh * WDIM + ww];
        drop[i] = (unsigned char)d;
        local += 1 - d;
    }
    atomicAdd(&s_count, local);
    __syncthreads();

    float scale = (float)HW / (float)s_count;  // sum of 0/1 is exact in fp32
    for (int i = threadIdx.x; i < HW; i += blockDim.x)
        m[i] = drop[i] ? 0.0f : scale;
}

// Kernel 2: streaming float4 multiply. Plane (56*56=3136 floats) is 784 float4s,
// and flat float4 index i maps to multiplier float4 index i % 784 exactly.
__global__ void __launch_bounds__(256) dropblock_apply_kernel(
        const float4* __restrict__ x, const float4* __restrict__ m4,
        float4* __restrict__ out, unsigned int nvec) {
    unsigned int i = blockIdx.x * 256u + threadIdx.x;
    if (i >= nvec) return;
    unsigned int p = i % (unsigned int)HW4;
    float4 xv = x[i];
    float4 mv = m4[p];
    float4 o;
    o.x = xv.x * mv.x;
    o.y = xv.y * mv.y;
    o.z = xv.z * mv.z;
    o.w = xv.w * mv.w;
    out[i] = o;
}

extern "C" void kernel_launch(void* const* d_in, const int* in_sizes, int n_in,
                              void* d_out, int out_size, void* d_ws, size_t ws_size,
                              hipStream_t stream) {
    const float* x = (const float*)d_in[0];   // (32,256,56,56) fp32
    const float* u = (const float*)d_in[1];   // (56,56) fp32
    float* out = (float*)d_out;
    float* m   = (float*)d_ws;                // 3136 floats of scratch

    dropblock_mask_kernel<<<1, 256, 0, stream>>>(u, m);

    unsigned int nvec = (unsigned int)(out_size / 4);   // 6,422,528 (exact)
    unsigned int blocks = (nvec + 255u) / 256u;
    dropblock_apply_kernel<<<blocks, 256, 0, stream>>>(
        (const float4*)x, (const float4*)m, (float4*)out, nvec);
}

// Round 3
// 181.724 us; speedup vs baseline: 1.1959x; 1.1959x over previous
//
#include <hip/hip_runtime.h>

// DropBlock: out[n,c,h,w] = x[n,c,h,w] * block_mask[h,w] * scale
// block_mask = 1 - maxpool7x7_backward(u < gamma); scale = HW / sum(block_mask)
//
// Mask kernel uses a bitboard: each 56-wide row is a uint64. Backward-looking
// 7-wide max (OR) dilation along W is OR of (row << k), k=0..6; along H it's
// an OR over the 7 preceding row bitmasks. One wave does the whole thing.

#define HW    3136   // 56*56
#define WDIM  56
#define HDIM  56
#define HW4   784    // HW/4
#define ROWMASK 0x00FFFFFFFFFFFFFFull  // low 56 bits

// clang native vector type — required by __builtin_nontemporal_load/store
typedef float vfloat4 __attribute__((ext_vector_type(4)));

__global__ void __launch_bounds__(256) dropblock_mask_kernel(
        const float* __restrict__ u, float* __restrict__ m) {
    __shared__ unsigned char seed[HW];
    __shared__ unsigned long long rowdil[HDIM];
    __shared__ unsigned long long dropbits[HDIM];
    __shared__ int rowkept[HDIM];
    __shared__ float s_scale;

    // gamma exactly as Python float64 arithmetic, then cast to f32 (JAX weak typing)
    const float gamma = (float)(0.1 / 49.0 * (3136.0 / 2500.0));

    // Phase 1: coalesced seed-bit generation (all 256 threads)
    for (int i = threadIdx.x; i < HW; i += 256)
        seed[i] = (u[i] < gamma) ? (unsigned char)1 : (unsigned char)0;
    __syncthreads();

    // Phase 2+3: one wave, lane r handles row r
    if (threadIdx.x < 64) {
        int r = threadIdx.x;
        if (r < HDIM) {
            unsigned long long rowmask = 0ull;
            const unsigned char* srow = &seed[r * WDIM];
            #pragma unroll
            for (int c = 0; c < WDIM; ++c)
                rowmask |= ((unsigned long long)srow[c]) << c;
            // W-dilation: dilated[w] = OR_{k=0..6} seed[w-k]
            unsigned long long rd = rowmask;
            #pragma unroll
            for (int k = 1; k < 7; ++k) rd |= (rowmask << k);
            rd &= ROWMASK;
            rowdil[r] = rd;
        }
        __builtin_amdgcn_wave_barrier();  // single wave: lockstep, LDS visible
        // H-dilation: drop[r] = OR_{j=r-6..r} rowdil[j]
        if (r < HDIM) {
            int j0 = (r >= 6) ? r - 6 : 0;
            unsigned long long d = 0ull;
            for (int j = j0; j <= r; ++j) d |= rowdil[j];
            d &= ROWMASK;
            dropbits[r] = d;
            rowkept[r] = WDIM - __popcll(d);
        }
    }
    __syncthreads();

    if (threadIdx.x == 0) {
        int total = 0;
        for (int r = 0; r < HDIM; ++r) total += rowkept[r];
        s_scale = (float)HW / (float)total;  // exact small-int arithmetic in fp32
    }
    __syncthreads();

    // Phase 4: write fused multiplier m[i] = drop ? 0 : scale (all 256 threads)
    float scale = s_scale;
    for (int i = threadIdx.x; i < HW; i += 256) {
        int r = i / WDIM, c = i % WDIM;
        m[i] = ((dropbits[r] >> c) & 1ull) ? 0.0f : scale;
    }
}

// Streaming float4 multiply. Plane (3136 floats) = 784 float4s; multiplier
// float4 index = flat float4 index % 784 (exact since 56 % 4 == 0).
__global__ void __launch_bounds__(256) dropblock_apply_kernel(
        const vfloat4* __restrict__ x, const vfloat4* __restrict__ m4,
        vfloat4* __restrict__ out, unsigned int nvec) {
    unsigned int i = blockIdx.x * 256u + threadIdx.x;
    if (i >= nvec) return;
    unsigned int p = i % (unsigned int)HW4;
    vfloat4 xv = __builtin_nontemporal_load(&x[i]);
    vfloat4 mv = m4[p];   // 12.5 KB table — keep cacheable
    vfloat4 o = xv * mv;
    __builtin_nontemporal_store(o, &out[i]);
}

extern "C" void kernel_launch(void* const* d_in, const int* in_sizes, int n_in,
                              void* d_out, int out_size, void* d_ws, size_t ws_size,
                              hipStream_t stream) {
    const float* x = (const float*)d_in[0];   // (32,256,56,56) fp32
    const float* u = (const float*)d_in[1];   // (56,56) fp32
    float* out = (float*)d_out;
    float* m   = (float*)d_ws;                // 3136 floats of scratch

    dropblock_mask_kernel<<<1, 256, 0, stream>>>(u, m);

    unsigned int nvec = (unsigned int)(out_size / 4);   // 6,422,528 (exact)
    unsigned int blocks = (nvec + 255u) / 256u;         // 25088
    dropblock_apply_kernel<<<blocks, 256, 0, stream>>>(
        (const vfloat4*)x, (const vfloat4*)m, (vfloat4*)out, nvec);
}

// Round 4
// 179.974 us; speedup vs baseline: 1.2075x; 1.0097x over previous
//
#include <hip/hip_runtime.h>

// DropBlock, fully fused single kernel.
// out[n,c,h,w] = x[n,c,h,w] * block_mask[h,w] * scale
// block_mask = 1 - maxpool7x7_backward(u < gamma); scale = HW / sum(block_mask)
//
// Every block redundantly computes the mask (bitboard dilation: 56-wide rows
// as uint64; W-dilation = OR of (row<<k) k=0..6; H-dilation = OR of 7 rows)
// into an LDS multiplier table, then grid-strides the 205.6 MB x->out stream.
// u is 12.5 KB — L2/L3-cached after the first blocks, so the redundancy is
// ~free; fusing removes the mask-kernel launch + stream serialization.

#define HW    3136   // 56*56
#define WDIM  56
#define HDIM  56
#define HW4   784    // HW/4
#define ROWMASK 0x00FFFFFFFFFFFFFFull  // low 56 bits
#define NBLOCKS 2048                   // 8 blocks/CU x 256 CUs
#define STRIDE  (NBLOCKS * 256u)       // 524288; 524288 % 784 == 576
#define PSTEP   576u

typedef float vfloat4 __attribute__((ext_vector_type(4)));

__global__ void __launch_bounds__(256) dropblock_fused_kernel(
        const float* __restrict__ u, const vfloat4* __restrict__ x,
        vfloat4* __restrict__ out, unsigned int nvec) {
    __shared__ unsigned char seed[HW];
    __shared__ unsigned long long rowdil[HDIM];
    __shared__ unsigned long long dropbits[HDIM];
    __shared__ int rowkept[HDIM];
    __shared__ float s_scale;
    __shared__ vfloat4 m4s[HW4];       // fused multiplier table, 12.25 KB

    // gamma exactly as Python float64 arithmetic, then cast to f32
    const float gamma = (float)(0.1 / 49.0 * (3136.0 / 2500.0));

    // Phase 1: seed bits (all 256 threads, coalesced u loads — L2/L3 hits)
    for (int i = threadIdx.x; i < HW; i += 256)
        seed[i] = (u[i] < gamma) ? (unsigned char)1 : (unsigned char)0;
    __syncthreads();

    // Phase 2: one wave, lane r handles row r
    if (threadIdx.x < 64) {
        int r = threadIdx.x;
        if (r < HDIM) {
            unsigned long long rowmask = 0ull;
            const unsigned char* srow = &seed[r * WDIM];
            #pragma unroll
            for (int c = 0; c < WDIM; ++c)
                rowmask |= ((unsigned long long)srow[c]) << c;
            unsigned long long rd = rowmask;
            #pragma unroll
            for (int k = 1; k < 7; ++k) rd |= (rowmask << k);
            rd &= ROWMASK;
            rowdil[r] = rd;
        }
        __builtin_amdgcn_wave_barrier();  // single wave: lockstep, LDS visible
        if (r < HDIM) {
            int j0 = (r >= 6) ? r - 6 : 0;
            unsigned long long d = 0ull;
            for (int j = j0; j <= r; ++j) d |= rowdil[j];
            d &= ROWMASK;
            dropbits[r] = d;
            rowkept[r] = WDIM - __popcll(d);
        }
    }
    __syncthreads();

    if (threadIdx.x == 0) {
        int total = 0;
        for (int r = 0; r < HDIM; ++r) total += rowkept[r];
        s_scale = (float)HW / (float)total;  // exact small-int arith in fp32
    }
    __syncthreads();

    // Phase 3: fused multiplier into LDS
    {
        float scale = s_scale;
        float* mf = (float*)m4s;
        for (int i = threadIdx.x; i < HW; i += 256) {
            int r = i / WDIM, c = i % WDIM;
            mf[i] = ((dropbits[r] >> c) & 1ull) ? 0.0f : scale;
        }
    }
    __syncthreads();

    // Phase 4: grid-stride streaming multiply.
    // Multiplier float4 index p = i % 784, maintained incrementally:
    // stride 524288 ≡ 576 (mod 784).
    unsigned int i = blockIdx.x * 256u + threadIdx.x;
    unsigned int p = i % (unsigned int)HW4;
    for (; i < nvec; i += STRIDE) {
        vfloat4 xv = __builtin_nontemporal_load(&x[i]);
        vfloat4 o = xv * m4s[p];
        __builtin_nontemporal_store(o, &out[i]);
        p += PSTEP;
        if (p >= (unsigned int)HW4) p -= (unsigned int)HW4;
    }
}

extern "C" void kernel_launch(void* const* d_in, const int* in_sizes, int n_in,
                              void* d_out, int out_size, void* d_ws, size_t ws_size,
                              hipStream_t stream) {
    const float* x = (const float*)d_in[0];   // (32,256,56,56) fp32
    const float* u = (const float*)d_in[1];   // (56,56) fp32
    float* out = (float*)d_out;

    unsigned int nvec = (unsigned int)(out_size / 4);   // 6,422,528 (exact)
    dropblock_fused_kernel<<<NBLOCKS, 256, 0, stream>>>(
        u, (const vfloat4*)x, (vfloat4*)out, nvec);
}